// Round 1
// baseline (223.717 us; speedup 1.0000x reference)
//
#include <hip/hip_runtime.h>
#include <math.h>

#define HH 256
#define NN 64
#define LL 4096
#define BB 8

// ws layout (floats):
//   [0]              dA_re  [H*N]
//   [16384]          dA_im  [H*N]
//   [32768]          w_re   [H*N]
//   [49152]          w_im   [H*N]
//   [65536]          g      [B*H]   (post-gelu last-position activations)

__global__ __launch_bounds__(256) void precompute_kernel(
    const float* __restrict__ log_dt, const float* __restrict__ A_log_re,
    const float* __restrict__ A_im, const float* __restrict__ B_re,
    const float* __restrict__ B_im, const float* __restrict__ C_re,
    const float* __restrict__ C_im,
    float* __restrict__ dA_re, float* __restrict__ dA_im,
    float* __restrict__ w_re, float* __restrict__ w_im) {
    int idx = blockIdx.x * blockDim.x + threadIdx.x;
    if (idx >= HH * NN) return;
    int h = idx / NN;
    float dt = expf(log_dt[h]);
    float Are = -expf(A_log_re[idx]);
    float Aim = A_im[idx];
    float dre = dt * Are, dim = dt * Aim;
    float ea = expf(dre);
    float sn, cs;
    sincosf(dim, &sn, &cs);
    float dAre = ea * cs, dAim = ea * sn;
    // q = (dA - 1) / A
    float numre = dAre - 1.0f, numim = dAim;
    float den = Are * Are + Aim * Aim;
    float qre = (numre * Are + numim * Aim) / den;
    float qim = (numim * Are - numre * Aim) / den;
    // dB = (B_re + i B_im) * q
    float bre = B_re[idx], bim = B_im[idx];
    float dBre = bre * qre - bim * qim;
    float dBim = bre * qim + bim * qre;
    // w = 2 * C0 * dB   (C is (2,H,N); channel 0 at [idx])
    float cre = C_re[idx], cim = C_im[idx];
    dA_re[idx] = dAre;
    dA_im[idx] = dAim;
    w_re[idx] = 2.0f * (cre * dBre - cim * dBim);
    w_im[idx] = 2.0f * (cre * dBim + cim * dBre);
}

// One block (64 threads = 1 wave) per (b,h). Lane = n.
__global__ __launch_bounds__(64) void scan_kernel(
    const int* __restrict__ input_ids, const float* __restrict__ emb,
    const float* __restrict__ dA_re, const float* __restrict__ dA_im,
    const float* __restrict__ w_re, const float* __restrict__ w_im,
    const float* __restrict__ D, float* __restrict__ g) {
    int bh = blockIdx.x;
    int b = bh >> 8;       // / H
    int h = bh & 255;      // % H
    int n = threadIdx.x;   // 0..63

    __shared__ float u_s[LL];

    // Stage u[b,h,:] into LDS: u[s] = emb[ids[s]*H + h]
    const int* idrow = input_ids + b * LL;
    #pragma unroll 4
    for (int s0 = 0; s0 < LL; s0 += 64) {
        int s = s0 + n;
        u_s[s] = emb[idrow[s] * HH + h];
    }
    __syncthreads();

    int idx = h * NN + n;
    float are = dA_re[idx], aim = dA_im[idx];
    float sre = 0.0f, sim = 0.0f;

    const float4* u4 = (const float4*)u_s;
    #pragma unroll 2
    for (int j = 0; j < LL / 4; ++j) {
        float4 uu = u4[j];
        float t;
        t = fmaf(sre, are, fmaf(sim, -aim, uu.x));
        sim = fmaf(sre, aim, sim * are);
        sre = t;
        t = fmaf(sre, are, fmaf(sim, -aim, uu.y));
        sim = fmaf(sre, aim, sim * are);
        sre = t;
        t = fmaf(sre, are, fmaf(sim, -aim, uu.z));
        sim = fmaf(sre, aim, sim * are);
        sre = t;
        t = fmaf(sre, are, fmaf(sim, -aim, uu.w));
        sim = fmaf(sre, aim, sim * are);
        sre = t;
    }

    // contribution = Re(w * S) = w_re*sre - w_im*sim
    float contrib = fmaf(w_re[idx], sre, -(w_im[idx] * sim));
    // full-wave reduction over n
    #pragma unroll
    for (int m = 32; m > 0; m >>= 1) contrib += __shfl_xor(contrib, m);

    if (n == 0) {
        float y = contrib + u_s[LL - 1] * D[h];
        // exact gelu: 0.5*y*(1+erf(y/sqrt(2)))
        float ge = 0.5f * y * (1.0f + erff(y * 0.70710678118654752f));
        g[b * HH + h] = ge;
    }
}

// One block per batch element; thread h computes both halves of z and GLU.
__global__ __launch_bounds__(256) void out_kernel(
    const float* __restrict__ g, const float* __restrict__ W,
    const float* __restrict__ bvec, float* __restrict__ out) {
    int b = blockIdx.x;
    int h = threadIdx.x;
    __shared__ float gs[HH];
    gs[h] = g[b * HH + h];
    __syncthreads();
    float z1 = bvec[h];
    float z2 = bvec[h + HH];
    const float* w1 = W + h * HH;
    const float* w2 = W + (h + HH) * HH;
    #pragma unroll 4
    for (int i = 0; i < HH; ++i) {
        z1 = fmaf(w1[i], gs[i], z1);
        z2 = fmaf(w2[i], gs[i], z2);
    }
    out[b * HH + h] = z1 * (1.0f / (1.0f + expf(-z2)));
}

extern "C" void kernel_launch(void* const* d_in, const int* in_sizes, int n_in,
                              void* d_out, int out_size, void* d_ws, size_t ws_size,
                              hipStream_t stream) {
    const int* input_ids = (const int*)d_in[0];
    const float* embedding = (const float*)d_in[1];
    const float* log_dt = (const float*)d_in[2];
    const float* A_log_re = (const float*)d_in[3];
    const float* A_im = (const float*)d_in[4];
    const float* B_re = (const float*)d_in[5];
    const float* B_im = (const float*)d_in[6];
    const float* C_re = (const float*)d_in[7];
    const float* C_im = (const float*)d_in[8];
    const float* D = (const float*)d_in[9];
    const float* W_out = (const float*)d_in[10];
    const float* b_out = (const float*)d_in[11];
    float* out = (float*)d_out;

    float* ws = (float*)d_ws;
    float* dA_re = ws;
    float* dA_im = ws + 16384;
    float* w_re = ws + 32768;
    float* w_im = ws + 49152;
    float* g = ws + 65536;

    precompute_kernel<<<(HH * NN + 255) / 256, 256, 0, stream>>>(
        log_dt, A_log_re, A_im, B_re, B_im, C_re, C_im, dA_re, dA_im, w_re, w_im);

    scan_kernel<<<BB * HH, 64, 0, stream>>>(
        input_ids, embedding, dA_re, dA_im, w_re, w_im, D, g);

    out_kernel<<<BB, 256, 0, stream>>>(g, W_out, b_out, out);
}

// Round 2
// 147.154 us; speedup vs baseline: 1.5203x; 1.5203x over previous
//
#include <hip/hip_runtime.h>
#include <math.h>

#define HH 256
#define NN 64
#define LL 4096
#define BB 8
#define CC 8            // L-chunks for parallelism
#define LC (LL / CC)    // 512
#define GG 16           // blocked-Horner group size
#define HN (HH * NN)    // 16384

// ws layout (floats):
//   dA   (float2[HN])          @ 0         (32768 floats)
//   wv   (float2[HN])          @ 32768     (32768)
//   pw   (float2[CC][HN])      @ 65536     (262144)
//   u_ws (float [B][H][L])     @ 327680    (8388608)
//   p_ws (float2[B][H][CC][N]) @ 8716288   (2097152)
//   g    (float [B][H])        @ 10813440  (2048)
// total ~10.8M floats = 41.3 MB

__global__ __launch_bounds__(256) void precompute_kernel(
    const float* __restrict__ log_dt, const float* __restrict__ A_log_re,
    const float* __restrict__ A_im, const float* __restrict__ B_re,
    const float* __restrict__ B_im, const float* __restrict__ C_re,
    const float* __restrict__ C_im,
    float2* __restrict__ dAo, float2* __restrict__ wo, float2* __restrict__ pw) {
    int idx = blockIdx.x * blockDim.x + threadIdx.x;  // h*64+n
    if (idx >= HN) return;
    int h = idx / NN;
    float dt = expf(log_dt[h]);
    float Are = -expf(A_log_re[idx]);
    float Aim = A_im[idx];
    float dre = dt * Are, dim = dt * Aim;
    float ea = expf(dre);
    float sn, cs;
    sincosf(dim, &sn, &cs);
    float dAre = ea * cs, dAim = ea * sn;
    // q = (dA - 1)/A ; dB = B*q ; w = 2*C0*dB
    float numre = dAre - 1.0f, numim = dAim;
    float den = Are * Are + Aim * Aim;
    float qre = (numre * Are + numim * Aim) / den;
    float qim = (numim * Are - numre * Aim) / den;
    float bre = B_re[idx], bim = B_im[idx];
    float dBre = bre * qre - bim * qim;
    float dBim = bre * qim + bim * qre;
    float cre = C_re[idx], cim = C_im[idx];
    dAo[idx] = make_float2(dAre, dAim);
    wo[idx] = make_float2(2.0f * (cre * dBre - cim * dBim),
                          2.0f * (cre * dBim + cim * dBre));
    // d512 = dA^512 via 9 squarings
    float pr = dAre, pi = dAim;
    #pragma unroll
    for (int k = 0; k < 9; ++k) {
        float nr = pr * pr - pi * pi;
        float ni = 2.0f * pr * pi;
        pr = nr; pi = ni;
    }
    // pw[k] = dA^(512*k)
    float qr = 1.0f, qi = 0.0f;
    #pragma unroll
    for (int k = 0; k < CC; ++k) {
        pw[k * HN + idx] = make_float2(qr, qi);
        float nr = qr * pr - qi * pi, ni = qr * pi + qi * pr;
        qr = nr; qi = ni;
    }
}

// Materialize u[b][h][s] = emb[ids[b][s]][h] with coalesced reads + LDS transpose.
// grid = B * 64 (s-tiles of 64), block = 256.
__global__ __launch_bounds__(256) void gather_kernel(
    const int* __restrict__ ids, const float* __restrict__ emb,
    float* __restrict__ u_ws) {
    int b = blockIdx.x >> 6;
    int tile = blockIdx.x & 63;
    int t = threadIdx.x;
    __shared__ int ids_s[64];
    __shared__ float tb[64][257];  // [s][h], padded: conflict-free transpose
    if (t < 64) ids_s[t] = ids[b * LL + tile * 64 + t];
    __syncthreads();
    #pragma unroll 4
    for (int r = 0; r < 64; ++r) {
        tb[r][t] = emb[ids_s[r] * HH + t];  // coalesced 1KB row read
    }
    __syncthreads();
    int w = t >> 6, lane = t & 63;
    #pragma unroll 4
    for (int r2 = 0; r2 < 64; ++r2) {
        int h = w * 64 + r2;
        // coalesced 256B store per wave-instr; LDS read banks (lane+h)%32: free
        u_ws[(b * HH + h) * LL + tile * 64 + lane] = tb[lane][h];
    }
}

// Chunked blocked-Horner scan. grid = B*H*CC (16384 waves), block = 64 (lane=n).
__global__ __launch_bounds__(64, 6) void scan_kernel(
    const float* __restrict__ u_ws, const float2* __restrict__ dAv,
    float2* __restrict__ p_ws) {
    int blk = blockIdx.x;       // (b*HH+h)*CC + c
    int c = blk & (CC - 1);
    int bh = blk >> 3;
    int h = bh & (HH - 1);
    int n = threadIdx.x;

    __shared__ float4 u_s[LC / 4];  // 512 floats = 2KB
    const float4* src = (const float4*)(u_ws + bh * LL + c * LC);
    u_s[n] = src[n];
    u_s[64 + n] = src[64 + n];
    __syncthreads();

    float2 dA = dAv[h * NN + n];
    // Qrev[k] = dA^(GG-1-k); R = dA^GG
    float Qr[GG], Qi[GG];
    float qr = 1.0f, qi = 0.0f;
    #pragma unroll
    for (int k = 0; k < GG; ++k) {
        Qr[GG - 1 - k] = qr; Qi[GG - 1 - k] = qi;
        float nr = qr * dA.x - qi * dA.y;
        float ni = qr * dA.y + qi * dA.x;
        qr = nr; qi = ni;
    }
    float Rr = qr, Ri = qi;

    float Pr = 0.0f, Pi = 0.0f;
    #pragma unroll 2
    for (int j = 0; j < LC / GG; ++j) {  // 32 groups
        float Tr = 0.0f, Ti = 0.0f;
        #pragma unroll
        for (int k4 = 0; k4 < GG / 4; ++k4) {
            float4 uu = u_s[j * (GG / 4) + k4];  // wave-uniform broadcast
            Tr = fmaf(uu.x, Qr[k4 * 4 + 0], Tr); Ti = fmaf(uu.x, Qi[k4 * 4 + 0], Ti);
            Tr = fmaf(uu.y, Qr[k4 * 4 + 1], Tr); Ti = fmaf(uu.y, Qi[k4 * 4 + 1], Ti);
            Tr = fmaf(uu.z, Qr[k4 * 4 + 2], Tr); Ti = fmaf(uu.z, Qi[k4 * 4 + 2], Ti);
            Tr = fmaf(uu.w, Qr[k4 * 4 + 3], Tr); Ti = fmaf(uu.w, Qi[k4 * 4 + 3], Ti);
        }
        float nr = fmaf(Pr, Rr, fmaf(Pi, -Ri, Tr));
        float ni = fmaf(Pr, Ri, fmaf(Pi, Rr, Ti));
        Pr = nr; Pi = ni;
    }
    p_ws[(bh * CC + c) * NN + n] = make_float2(Pr, Pi);
}

// Combine chunk partials, project through C, add D-term, gelu.
// grid = B*H (2048 waves), block = 64.
__global__ __launch_bounds__(64) void combine_kernel(
    const float2* __restrict__ p_ws, const float2* __restrict__ pw,
    const float2* __restrict__ wv, const float* __restrict__ u_ws,
    const float* __restrict__ D, float* __restrict__ g) {
    int bh = blockIdx.x;
    int h = bh & (HH - 1);
    int n = threadIdx.x;
    float Sr = 0.0f, Si = 0.0f;
    #pragma unroll
    for (int c = 0; c < CC; ++c) {
        float2 P = p_ws[(bh * CC + c) * NN + n];
        float2 Wp = pw[(CC - 1 - c) * HN + h * NN + n];
        Sr = fmaf(P.x, Wp.x, fmaf(P.y, -Wp.y, Sr));
        Si = fmaf(P.x, Wp.y, fmaf(P.y, Wp.x, Si));
    }
    float2 wc = wv[h * NN + n];
    float contrib = fmaf(wc.x, Sr, -(wc.y * Si));
    #pragma unroll
    for (int m = 32; m > 0; m >>= 1) contrib += __shfl_xor(contrib, m);
    if (n == 0) {
        float y = contrib + u_ws[bh * LL + LL - 1] * D[h];
        float ge = 0.5f * y * (1.0f + erff(y * 0.70710678118654752f));
        g[bh] = ge;
    }
}

// Output projection + GLU. grid = B*128 (2 h per block), block = 256 (4 waves).
// Wave w: h = tile*2 + (w>>1), o = (w&1)*HH + h. Coalesced float4 row reads.
__global__ __launch_bounds__(256) void out_kernel(
    const float* __restrict__ g, const float* __restrict__ W,
    const float* __restrict__ bvec, float* __restrict__ out) {
    int b = blockIdx.x >> 7;
    int tile = blockIdx.x & 127;
    int t = threadIdx.x;
    int w = t >> 6, lane = t & 63;
    __shared__ float gs[HH];
    __shared__ float zb[4];
    gs[t] = g[b * HH + t];
    __syncthreads();
    int hh = tile * 2 + (w >> 1);
    int o = (w & 1) * HH + hh;
    float4 wv4 = ((const float4*)(W + o * HH))[lane];
    float4 gv4 = ((const float4*)gs)[lane];
    float p = wv4.x * gv4.x + wv4.y * gv4.y + wv4.z * gv4.z + wv4.w * gv4.w;
    #pragma unroll
    for (int m = 32; m > 0; m >>= 1) p += __shfl_xor(p, m);
    if (lane == 0) zb[w] = p + bvec[o];
    __syncthreads();
    if (t < 2) {
        int hq = tile * 2 + t;
        float z1 = zb[t * 2 + 0];
        float z2 = zb[t * 2 + 1];
        out[b * HH + hq] = z1 * (1.0f / (1.0f + expf(-z2)));
    }
}

extern "C" void kernel_launch(void* const* d_in, const int* in_sizes, int n_in,
                              void* d_out, int out_size, void* d_ws, size_t ws_size,
                              hipStream_t stream) {
    const int* input_ids = (const int*)d_in[0];
    const float* embedding = (const float*)d_in[1];
    const float* log_dt = (const float*)d_in[2];
    const float* A_log_re = (const float*)d_in[3];
    const float* A_im = (const float*)d_in[4];
    const float* B_re = (const float*)d_in[5];
    const float* B_im = (const float*)d_in[6];
    const float* C_re = (const float*)d_in[7];
    const float* C_im = (const float*)d_in[8];
    const float* D = (const float*)d_in[9];
    const float* W_out = (const float*)d_in[10];
    const float* b_out = (const float*)d_in[11];
    float* out = (float*)d_out;

    float* ws = (float*)d_ws;
    float2* dAv = (float2*)ws;                    // HN float2
    float2* wv = (float2*)(ws + 32768);           // HN float2
    float2* pw = (float2*)(ws + 65536);           // CC*HN float2
    float* u_ws = ws + 327680;                    // B*H*L floats
    float2* p_ws = (float2*)(ws + 8716288);       // B*H*CC*N float2
    float* g = ws + 10813440;                     // B*H floats

    precompute_kernel<<<(HN + 255) / 256, 256, 0, stream>>>(
        log_dt, A_log_re, A_im, B_re, B_im, C_re, C_im, dAv, wv, pw);

    gather_kernel<<<BB * 64, 256, 0, stream>>>(input_ids, embedding, u_ws);

    scan_kernel<<<BB * HH * CC, 64, 0, stream>>>(u_ws, dAv, p_ws);

    combine_kernel<<<BB * HH, 64, 0, stream>>>(p_ws, pw, wv, u_ws, D, g);

    out_kernel<<<BB * 128, 256, 0, stream>>>(g, W_out, b_out, out);
}